// Round 19
// baseline (284.227 us; speedup 1.0000x reference)
//
#include <hip/hip_runtime.h>

#define TOKENS 16384
#define DDIM 4096
#define RANK 32
#define TOPK 8
#define KCH 8        // K-chunks -> y_part planes (512 dims each)
#define TAU 2e-3f    // routing-gap margin: flag if below
#define ROWF 260     // LDS floats per x row: 256 + 4 pad

typedef __attribute__((ext_vector_type(8))) short bf16x8;  // 8 bf16 (4 VGPR)
typedef __attribute__((ext_vector_type(4))) float f32x4;

// global -> LDS async DMA, 16B per lane (wave-uniform LDS base + lane*16)
__device__ __forceinline__ void dma16(const float* g, float* l) {
  __builtin_amdgcn_global_load_lds(
      (const __attribute__((address_space(1))) unsigned int*)g,
      (__attribute__((address_space(3))) unsigned int*)l, 16, 0, 0);
}

// ---------------- K0a: pack A into MFMA-fragment order, hi/lo bf16 --------
__global__ __launch_bounds__(256) void k0_packA(const float* __restrict__ A,
                                                bf16x8* __restrict__ Apk,
                                                int* __restrict__ flag_cnt) {
  const int i = blockIdx.x * 256 + threadIdx.x;  // 0 .. 32767
  if (i == 0) *flag_cnt = 0;
  const int lane = i & 63;
  const int s = (i >> 6) & 3;
  const int ks = (i >> 8) & 15;
  const int kc = i >> 12;
  const int mrow = lane & 15;
  const int kg = lane >> 4;
  const int row = (s & 1) ? mrow + 16 : mrow;
  const int col = kc * 512 + ks * 32 + kg * 8;
  const float* src = &A[(size_t)row * DDIM + col];
  bf16x8 o;
#pragma unroll
  for (int j = 0; j < 8; ++j) {
    const float a = src[j];
    const unsigned b = __float_as_uint(a);
    if (s < 2) {
      o[j] = (short)(b >> 16);  // hi = truncate-to-bf16
    } else {
      const float hf = __uint_as_float(b & 0xFFFF0000u);
      const float r = a - hf;   // lo = residual as bf16
      o[j] = (short)(__float_as_uint(r) >> 16);
    }
  }
  Apk[i] = o;
}

// ---------------- K0b: pack B into MFMA B-operand fragment order ----------
// Bpk[ct*512 + lane*8 + j] = bf16(B[ct*16 + (lane&15)][(lane>>4)*8 + j]).
// bf16 B is fine for the OUTPUT: threshold 2.5e-2 >> bf16-induced ~3e-3.
__global__ __launch_bounds__(256) void k0_packB(const float* __restrict__ B,
                                                ushort* __restrict__ Bpk) {
  const int i = blockIdx.x * 256 + threadIdx.x;  // 0 .. 16383
  const int lane = i & 63;
  const int ct = i >> 6;
  const int col = ct * 16 + (lane & 15);
  const int r0 = (lane >> 4) * 8;
  const float* src = &B[(size_t)col * RANK + r0];
  bf16x8 o;
#pragma unroll
  for (int j = 0; j < 8; ++j)
    o[j] = (short)(__float_as_uint(src[j]) >> 16);
  *reinterpret_cast<bf16x8*>(&Bpk[(size_t)i * 8]) = o;
}

// ---------------- K1: y_part[kc][t][r] via mfma_f32_16x16x32_bf16 ----------
// r18 counters: k1 was latency-SERIALIZED (VALUBusy 9.5%, dur independent of
// HBM traffic). Fix: 4 waves = 2 token-tiles x 2 rank-halves; each wave
// DMA-fills ONE (tile,sub) buffer -> all 32 fills of the block in flight at
// once -> ONE __syncthreads (drains vmcnt) -> each wave computes all 16
// K-steps uninterrupted (3 MFMAs/ks for its 16-rank half). 66.5 KB LDS
// (2 blocks/CU: block Y fills while X computes). Fragment maps = r13/r17.
__global__ __launch_bounds__(256) void k1_mfma(const float* __restrict__ x,
                                               const bf16x8* __restrict__ Apk,
                                               float* __restrict__ y_part) {
  const int tid = threadIdx.x;
  const int lane = tid & 63;
  const int wid = __builtin_amdgcn_readfirstlane(tid >> 6);
  const int tile = wid >> 1;  // 0..1: which 16-token tile
  const int rh = wid & 1;     // 0..1: which 16-rank half
  const int t0 = blockIdx.x * 32 + tile * 16;
  const int kc = blockIdx.y;

  __shared__ float xs[2 * 2 * 16 * ROWF];  // [tile][sub][row][260] = 66,560B

  // this wave fills sub=rh of its tile: 16 rows x 1KB, 16 DMAs in flight
  float* fdst = &xs[(tile * 2 + rh) * 16 * ROWF];
#pragma unroll
  for (int r = 0; r < 16; ++r)
    dma16(&x[(size_t)(t0 + r) * DDIM + kc * 512 + rh * 256 + lane * 4],
          fdst + r * ROWF);

  __syncthreads();  // compiler drains vmcnt(0) -> both subs of both tiles ready

  const int mrow = lane & 15;  // token (A-op) / rank (B-op)
  const int kg = lane >> 4;    // k-group of 8 dims
  f32x4 acc = {0.f, 0.f, 0.f, 0.f};
  const bf16x8* ap = Apk + ((size_t)kc << 12) + lane;
  const float* tb = &xs[tile * 2 * 16 * ROWF];

#pragma unroll
  for (int ks = 0; ks < 16; ++ks) {
    const int sub = ks >> 3, ks8 = ks & 7;
    const float* xrow = tb + sub * 16 * ROWF + mrow * ROWF + ks8 * 32 + kg * 8;
    const float4 f0 = *reinterpret_cast<const float4*>(xrow);
    const float4 f1 = *reinterpret_cast<const float4*>(xrow + 4);

    const bf16x8 bh = ap[(ks * 4 + rh) * 64];      // hi stream, this half
    const bf16x8 bl = ap[(ks * 4 + 2 + rh) * 64];  // lo stream, this half

    const float xf[8] = {f0.x, f0.y, f0.z, f0.w, f1.x, f1.y, f1.z, f1.w};
    bf16x8 xh, xl;
#pragma unroll
    for (int j = 0; j < 8; ++j) {  // constant indices only (no scratch)
      const unsigned b = __float_as_uint(xf[j]);
      xh[j] = (short)(b >> 16);
      const float rr = xf[j] - __uint_as_float(b & 0xFFFF0000u);
      xl[j] = (short)(__float_as_uint(rr) >> 16);
    }

    acc = __builtin_amdgcn_mfma_f32_16x16x32_bf16(xh, bh, acc, 0, 0, 0);
    acc = __builtin_amdgcn_mfma_f32_16x16x32_bf16(xh, bl, acc, 0, 0, 0);
    acc = __builtin_amdgcn_mfma_f32_16x16x32_bf16(xl, bh, acc, 0, 0, 0);
  }

  // D: token = t0 + kg*4 + i, rank = rh*16 + mrow
  float* yp =
      &y_part[((size_t)kc * TOKENS + t0 + kg * 4) * RANK + rh * 16 + mrow];
#pragma unroll
  for (int i = 0; i < 4; ++i) yp[(size_t)i * RANK] = acc[i];
}

// ---------------- K2: reduce, top-8 + gap margin; emit bf16 w_pk ----------
__global__ __launch_bounds__(64) void k2_topk(const float* __restrict__ y_part,
                                              const float* __restrict__ dbias,
                                              ushort* __restrict__ w_pk,
                                              int* __restrict__ flag_cnt,
                                              int* __restrict__ flag_list) {
  const int t = blockIdx.x * 64 + threadIdx.x;
  float yv[RANK];
#pragma unroll
  for (int r = 0; r < RANK; ++r) yv[r] = 0.f;
#pragma unroll
  for (int c = 0; c < KCH; ++c) {
    const float* yp = &y_part[((size_t)c * TOKENS + t) * RANK];
#pragma unroll
    for (int q = 0; q < RANK / 4; ++q) {
      const float4 v = reinterpret_cast<const float4*>(yp)[q];
      yv[q * 4 + 0] += v.x; yv[q * 4 + 1] += v.y;
      yv[q * 4 + 2] += v.z; yv[q * 4 + 3] += v.w;
    }
  }

  float ab[RANK];
#pragma unroll
  for (int r = 0; r < RANK; ++r) ab[r] = fabsf(yv[r] + dbias[r]);

  unsigned mask = 0;
  float best8 = 0.f;
#pragma unroll
  for (int k = 0; k < TOPK; ++k) {
    float best = -1.f;
    int bi = 0;
#pragma unroll
    for (int r = 0; r < RANK; ++r) {
      // strict > keeps lowest index on ties == jax.lax.top_k stability
      const bool sel = (((mask >> r) & 1u) == 0u) && (ab[r] > best);
      best = sel ? ab[r] : best;
      bi = sel ? r : bi;
    }
    mask |= 1u << bi;
    best8 = best;
  }
  float ninth = -1.f;
#pragma unroll
  for (int r = 0; r < RANK; ++r) {
    const bool un = ((mask >> r) & 1u) == 0u;
    ninth = (un && ab[r] > ninth) ? ab[r] : ninth;
  }
  if (best8 - ninth < TAU) {  // split-y can't certify fp32 decision
    const int idx = atomicAdd(flag_cnt, 1);
    flag_list[idx] = t;
  }

  // w = 2*y*mask, packed to bf16 (rank-order == MFMA A-op fragment order)
  ushort* wp = &w_pk[(size_t)t * RANK];
  unsigned up[16];
#pragma unroll
  for (int h = 0; h < 16; ++h) {
    const float a = ((mask >> (2 * h)) & 1u) ? 2.0f * yv[2 * h] : 0.f;
    const float b = ((mask >> (2 * h + 1)) & 1u) ? 2.0f * yv[2 * h + 1] : 0.f;
    up[h] = (__float_as_uint(a) >> 16) | (__float_as_uint(b) & 0xFFFF0000u);
  }
#pragma unroll
  for (int q = 0; q < 4; ++q) {
    uint4 v = {up[4 * q], up[4 * q + 1], up[4 * q + 2], up[4 * q + 3]};
    reinterpret_cast<uint4*>(wp)[q] = v;
  }
}

// ---------------- K2b: exact fp32 re-route for flagged tokens -------------
__global__ __launch_bounds__(256) void k2b_refine(
    const float* __restrict__ x, const float* __restrict__ A,
    const float* __restrict__ dbias, const int* __restrict__ flag_cnt,
    const int* __restrict__ flag_list, ushort* __restrict__ w_pk) {
  __shared__ float part[8][RANK];
  __shared__ float yv_s[RANK];
  __shared__ unsigned mask_s;
  const int cnt = *flag_cnt;
  const int rank = threadIdx.x & 31;
  const int seg = threadIdx.x >> 5;

  for (int i = blockIdx.x; i < cnt; i += gridDim.x) {
    const int t = flag_list[i];
    const float4* xr =
        reinterpret_cast<const float4*>(&x[(size_t)t * DDIM + seg * 512]);
    const float4* Ar =
        reinterpret_cast<const float4*>(&A[(size_t)rank * DDIM + seg * 512]);
    float s = 0.f;
    for (int c = 0; c < 128; c += 4) {  // 16-dim sub-sums, two-level fp32
      float ss = 0.f;
#pragma unroll
      for (int u = 0; u < 4; ++u) {
        const float4 xv = xr[c + u];
        const float4 av = Ar[c + u];
        ss = fmaf(xv.x, av.x, ss);
        ss = fmaf(xv.y, av.y, ss);
        ss = fmaf(xv.z, av.z, ss);
        ss = fmaf(xv.w, av.w, ss);
      }
      s += ss;
    }
    part[seg][rank] = s;
    __syncthreads();
    if (threadIdx.x < 32) {
      float y = 0.f;
#pragma unroll
      for (int g = 0; g < 8; ++g) y += part[g][threadIdx.x];
      yv_s[threadIdx.x] = y;
    }
    __syncthreads();
    if (threadIdx.x == 0) {
      float ab[RANK];
#pragma unroll
      for (int r = 0; r < RANK; ++r) ab[r] = fabsf(yv_s[r] + dbias[r]);
      unsigned mask = 0;
#pragma unroll
      for (int k = 0; k < TOPK; ++k) {
        float best = -1.f;
        int bi = 0;
#pragma unroll
        for (int r = 0; r < RANK; ++r) {
          const bool sel = (((mask >> r) & 1u) == 0u) && (ab[r] > best);
          best = sel ? ab[r] : best;
          bi = sel ? r : bi;
        }
        mask |= 1u << bi;
      }
      mask_s = mask;
    }
    __syncthreads();
    if (threadIdx.x < 32) {
      const float v = ((mask_s >> rank) & 1u) ? 2.0f * yv_s[rank] : 0.f;
      w_pk[(size_t)t * RANK + rank] = (ushort)(__float_as_uint(v) >> 16);
    }
    __syncthreads();  // protect LDS reuse next iteration
  }
}

// ---------------- K3: out = w @ B^T via MFMA ------------------------------
// Replaces the DS-broadcast FMA kernel (~78us, DS-pipe-serialized: 4 waves
// re-broadcasting the same w rows). Per 16tok x 16col tile: 1 coalesced
// w-frag load (reused over 16 col-tiles), 1 Bpk load (L2-hot), 1 MFMA,
// 4 stores (4x64B segments). No LDS, no barriers. K=32 = full rank.
__global__ __launch_bounds__(256) void k3_mfma(const ushort* __restrict__ w_pk,
                                               const ushort* __restrict__ Bpk,
                                               float* __restrict__ out) {
  const int tid = threadIdx.x;
  const int lane = tid & 63;
  const int wid = __builtin_amdgcn_readfirstlane(tid >> 6);
  const int t0 = (blockIdx.x * 4 + wid) * 16;
  const int mrow = lane & 15;
  const int kg = lane >> 4;

  const bf16x8 wf = *reinterpret_cast<const bf16x8*>(
      &w_pk[(size_t)(t0 + mrow) * RANK + kg * 8]);
  const int ct0 = blockIdx.y * 16;  // 16 col-tiles = 256 columns per block

#pragma unroll
  for (int j = 0; j < 16; ++j) {
    const bf16x8 bf = *reinterpret_cast<const bf16x8*>(
        &Bpk[(size_t)(ct0 + j) * 512 + lane * 8]);
    f32x4 acc = {0.f, 0.f, 0.f, 0.f};
    acc = __builtin_amdgcn_mfma_f32_16x16x32_bf16(wf, bf, acc, 0, 0, 0);
    // D: token = t0 + kg*4 + i, col = (ct0+j)*16 + mrow
    float* op = &out[(size_t)(t0 + kg * 4) * DDIM + (ct0 + j) * 16 + mrow];
#pragma unroll
    for (int i = 0; i < 4; ++i) op[(size_t)i * DDIM] = acc[i];
  }
}

extern "C" void kernel_launch(void* const* d_in, const int* in_sizes, int n_in,
                              void* d_out, int out_size, void* d_ws,
                              size_t ws_size, hipStream_t stream) {
  const float* x = (const float*)d_in[0];
  const float* A = (const float*)d_in[1];
  const float* B = (const float*)d_in[2];
  const float* dbias = (const float*)d_in[3];
  float* out = (float*)d_out;

  const size_t plane = (size_t)TOKENS * RANK;     // 512K floats = 2 MB
  float* y_part = (float*)d_ws;                   // KCH planes (16 MB)
  ushort* w_pk = (ushort*)(y_part + KCH * plane); // 1 MB bf16
  bf16x8* Apk = (bf16x8*)(w_pk + (size_t)TOKENS * RANK);  // 512 KB
  ushort* Bpk = (ushort*)(Apk + 32768);           // 256 KB
  int* flag_cnt = (int*)(Bpk + (size_t)DDIM * RANK);
  int* flag_list = flag_cnt + 4;                  // capacity TOKENS (64 KB)

  k0_packA<<<128, 256, 0, stream>>>(A, Apk, flag_cnt);
  k0_packB<<<64, 256, 0, stream>>>(B, Bpk);
  k1_mfma<<<dim3(TOKENS / 32, KCH), 256, 0, stream>>>(x, Apk, y_part);
  k2_topk<<<TOKENS / 64, 64, 0, stream>>>(y_part, dbias, w_pk, flag_cnt,
                                          flag_list);
  k2b_refine<<<512, 256, 0, stream>>>(x, A, dbias, flag_cnt, flag_list, w_pk);
  k3_mfma<<<dim3(TOKENS / 64, DDIM / 256), 256, 0, stream>>>(w_pk, Bpk, out);
}

// Round 20
// 207.803 us; speedup vs baseline: 1.3678x; 1.3678x over previous
//
#include <hip/hip_runtime.h>

#define TOKENS 16384
#define DDIM 4096
#define RANK 32
#define TOPK 8
#define KCH 8        // K-chunks -> y_part planes (512 dims each)
#define TAU 2e-3f    // routing-gap margin: flag if below
#define ROWF 260     // LDS floats per x row: 256 + 4 pad

typedef __attribute__((ext_vector_type(8))) short bf16x8;  // 8 bf16 (4 VGPR)
typedef __attribute__((ext_vector_type(4))) float f32x4;

// global -> LDS async DMA, 16B per lane (wave-uniform LDS base + lane*16)
__device__ __forceinline__ void dma16(const float* g, float* l) {
  __builtin_amdgcn_global_load_lds(
      (const __attribute__((address_space(1))) unsigned int*)g,
      (__attribute__((address_space(3))) unsigned int*)l, 16, 0, 0);
}

// ---------------- K0a: pack A into MFMA-fragment order, hi/lo bf16 --------
__global__ __launch_bounds__(256) void k0_packA(const float* __restrict__ A,
                                                bf16x8* __restrict__ Apk,
                                                int* __restrict__ flag_cnt) {
  const int i = blockIdx.x * 256 + threadIdx.x;  // 0 .. 32767
  if (i == 0) *flag_cnt = 0;
  const int lane = i & 63;
  const int s = (i >> 6) & 3;
  const int ks = (i >> 8) & 15;
  const int kc = i >> 12;
  const int mrow = lane & 15;
  const int kg = lane >> 4;
  const int row = (s & 1) ? mrow + 16 : mrow;
  const int col = kc * 512 + ks * 32 + kg * 8;
  const float* src = &A[(size_t)row * DDIM + col];
  bf16x8 o;
#pragma unroll
  for (int j = 0; j < 8; ++j) {
    const float a = src[j];
    const unsigned b = __float_as_uint(a);
    if (s < 2) {
      o[j] = (short)(b >> 16);  // hi = truncate-to-bf16
    } else {
      const float hf = __uint_as_float(b & 0xFFFF0000u);
      const float r = a - hf;   // lo = residual as bf16
      o[j] = (short)(__float_as_uint(r) >> 16);
    }
  }
  Apk[i] = o;
}

// ---------------- K0b: pack B into MFMA B-operand fragment order ----------
__global__ __launch_bounds__(256) void k0_packB(const float* __restrict__ B,
                                                ushort* __restrict__ Bpk) {
  const int i = blockIdx.x * 256 + threadIdx.x;  // 0 .. 16383
  const int lane = i & 63;
  const int ct = i >> 6;
  const int col = ct * 16 + (lane & 15);
  const int r0 = (lane >> 4) * 8;
  const float* src = &B[(size_t)col * RANK + r0];
  bf16x8 o;
#pragma unroll
  for (int j = 0; j < 8; ++j)
    o[j] = (short)(__float_as_uint(src[j]) >> 16);
  *reinterpret_cast<bf16x8*>(&Bpk[(size_t)i * 8]) = o;
}

// ---------------- K1: y_part[kc][t][r] via mfma_f32_16x16x32_bf16 ----------
// r17-EXACT (best measured: ~105us by r18 z-scaling). y ~= xh*Ah + xh*Al +
// xl*Ah; routing certified in k2 / fixed in k2b. x via global_load_lds DMA;
// A from Apk: 4 coalesced loads per K-step, L2-resident.
__global__ __launch_bounds__(256) void k1_mfma(const float* __restrict__ x,
                                               const bf16x8* __restrict__ Apk,
                                               float* __restrict__ y_part) {
  const int tid = threadIdx.x;
  const int lane = tid & 63;
  const int wv = __builtin_amdgcn_readfirstlane(tid >> 6);
  const int t0 = blockIdx.x * 64 + wv * 16;
  const int kc = blockIdx.y;

  __shared__ float xs[4 * 16 * ROWF];  // 66,560 B -> 2 blocks/CU
  float* xw = &xs[wv * 16 * ROWF];

  const int mrow = lane & 15;  // token (A-op) / rank (B-op)
  const int kg = lane >> 4;    // k-group of 8 dims

  f32x4 acc0 = {0.f, 0.f, 0.f, 0.f};  // ranks 0..15
  f32x4 acc1 = {0.f, 0.f, 0.f, 0.f};  // ranks 16..31

  const bf16x8* ap = Apk + ((size_t)kc << 12) + lane;  // 4096 frags per kc

  // ---- DMA sub0: 16 rows x 1KB, all 16 outstanding ----
#pragma unroll
  for (int r = 0; r < 16; ++r)
    dma16(&x[(size_t)(t0 + r) * DDIM + kc * 512 + lane * 4], xw + r * ROWF);

#pragma unroll
  for (int sub = 0; sub < 2; ++sub) {
    asm volatile("s_waitcnt vmcnt(0)" ::: "memory");  // this wave's DMAs done
    __builtin_amdgcn_sched_barrier(0);

#pragma unroll
    for (int ks8 = 0; ks8 < 8; ++ks8) {
      const int ks = sub * 8 + ks8;
      const float* xrow = xw + mrow * ROWF + ks8 * 32 + kg * 8;
      const float4 f0 = *reinterpret_cast<const float4*>(xrow);
      const float4 f1 = *reinterpret_cast<const float4*>(xrow + 4);

      const bf16x8 bh0 = ap[(ks * 4 + 0) * 64];
      const bf16x8 bh1 = ap[(ks * 4 + 1) * 64];
      const bf16x8 bl0 = ap[(ks * 4 + 2) * 64];
      const bf16x8 bl1 = ap[(ks * 4 + 3) * 64];

      const float xf[8] = {f0.x, f0.y, f0.z, f0.w, f1.x, f1.y, f1.z, f1.w};
      bf16x8 xh, xl;
#pragma unroll
      for (int j = 0; j < 8; ++j) {  // constant indices only (no scratch)
        const unsigned b = __float_as_uint(xf[j]);
        xh[j] = (short)(b >> 16);
        const float rr = xf[j] - __uint_as_float(b & 0xFFFF0000u);
        xl[j] = (short)(__float_as_uint(rr) >> 16);
      }

      acc0 = __builtin_amdgcn_mfma_f32_16x16x32_bf16(xh, bh0, acc0, 0, 0, 0);
      acc1 = __builtin_amdgcn_mfma_f32_16x16x32_bf16(xh, bh1, acc1, 0, 0, 0);
      acc0 = __builtin_amdgcn_mfma_f32_16x16x32_bf16(xh, bl0, acc0, 0, 0, 0);
      acc1 = __builtin_amdgcn_mfma_f32_16x16x32_bf16(xh, bl1, acc1, 0, 0, 0);
      acc0 = __builtin_amdgcn_mfma_f32_16x16x32_bf16(xl, bh0, acc0, 0, 0, 0);
      acc1 = __builtin_amdgcn_mfma_f32_16x16x32_bf16(xl, bh1, acc1, 0, 0, 0);
    }

    if (sub == 0) {
      // all ds_reads of sub0 delivered before overwriting the buffer
      asm volatile("s_waitcnt lgkmcnt(0)" ::: "memory");
      __builtin_amdgcn_sched_barrier(0);
#pragma unroll
      for (int r = 0; r < 16; ++r)
        dma16(&x[(size_t)(t0 + r) * DDIM + kc * 512 + 256 + lane * 4],
              xw + r * ROWF);
    }
  }

  // D: token = t0 + kg*4 + i, rank = mrow (acc0) / mrow+16 (acc1)
  float* yp = &y_part[((size_t)kc * TOKENS + t0 + kg * 4) * RANK + mrow];
#pragma unroll
  for (int i = 0; i < 4; ++i) {
    yp[(size_t)i * RANK] = acc0[i];
    yp[(size_t)i * RANK + 16] = acc1[i];
  }
}

// ---------------- K2: reduce, top-8 + gap margin; emit bf16 w_pk ----------
__global__ __launch_bounds__(64) void k2_topk(const float* __restrict__ y_part,
                                              const float* __restrict__ dbias,
                                              ushort* __restrict__ w_pk,
                                              int* __restrict__ flag_cnt,
                                              int* __restrict__ flag_list) {
  const int t = blockIdx.x * 64 + threadIdx.x;
  float yv[RANK];
#pragma unroll
  for (int r = 0; r < RANK; ++r) yv[r] = 0.f;
#pragma unroll
  for (int c = 0; c < KCH; ++c) {
    const float* yp = &y_part[((size_t)c * TOKENS + t) * RANK];
#pragma unroll
    for (int q = 0; q < RANK / 4; ++q) {
      const float4 v = reinterpret_cast<const float4*>(yp)[q];
      yv[q * 4 + 0] += v.x; yv[q * 4 + 1] += v.y;
      yv[q * 4 + 2] += v.z; yv[q * 4 + 3] += v.w;
    }
  }

  float ab[RANK];
#pragma unroll
  for (int r = 0; r < RANK; ++r) ab[r] = fabsf(yv[r] + dbias[r]);

  unsigned mask = 0;
  float best8 = 0.f;
#pragma unroll
  for (int k = 0; k < TOPK; ++k) {
    float best = -1.f;
    int bi = 0;
#pragma unroll
    for (int r = 0; r < RANK; ++r) {
      // strict > keeps lowest index on ties == jax.lax.top_k stability
      const bool sel = (((mask >> r) & 1u) == 0u) && (ab[r] > best);
      best = sel ? ab[r] : best;
      bi = sel ? r : bi;
    }
    mask |= 1u << bi;
    best8 = best;
  }
  float ninth = -1.f;
#pragma unroll
  for (int r = 0; r < RANK; ++r) {
    const bool un = ((mask >> r) & 1u) == 0u;
    ninth = (un && ab[r] > ninth) ? ab[r] : ninth;
  }
  if (best8 - ninth < TAU) {  // split-y can't certify fp32 decision
    const int idx = atomicAdd(flag_cnt, 1);
    flag_list[idx] = t;
  }

  // w = 2*y*mask, packed to bf16 (natural rank order == A-op fragment order)
  ushort* wp = &w_pk[(size_t)t * RANK];
  unsigned up[16];
#pragma unroll
  for (int h = 0; h < 16; ++h) {
    const float a = ((mask >> (2 * h)) & 1u) ? 2.0f * yv[2 * h] : 0.f;
    const float b = ((mask >> (2 * h + 1)) & 1u) ? 2.0f * yv[2 * h + 1] : 0.f;
    up[h] = (__float_as_uint(a) >> 16) | (__float_as_uint(b) & 0xFFFF0000u);
  }
#pragma unroll
  for (int q = 0; q < 4; ++q) {
    uint4 v = {up[4 * q], up[4 * q + 1], up[4 * q + 2], up[4 * q + 3]};
    reinterpret_cast<uint4*>(wp)[q] = v;
  }
}

// ---------------- K2b: exact fp32 re-route for flagged tokens -------------
__global__ __launch_bounds__(256) void k2b_refine(
    const float* __restrict__ x, const float* __restrict__ A,
    const float* __restrict__ dbias, const int* __restrict__ flag_cnt,
    const int* __restrict__ flag_list, ushort* __restrict__ w_pk) {
  __shared__ float part[8][RANK];
  __shared__ float yv_s[RANK];
  __shared__ unsigned mask_s;
  const int cnt = *flag_cnt;
  const int rank = threadIdx.x & 31;
  const int seg = threadIdx.x >> 5;

  for (int i = blockIdx.x; i < cnt; i += gridDim.x) {
    const int t = flag_list[i];
    const float4* xr =
        reinterpret_cast<const float4*>(&x[(size_t)t * DDIM + seg * 512]);
    const float4* Ar =
        reinterpret_cast<const float4*>(&A[(size_t)rank * DDIM + seg * 512]);
    float s = 0.f;
    for (int c = 0; c < 128; c += 4) {  // 16-dim sub-sums, two-level fp32
      float ss = 0.f;
#pragma unroll
      for (int u = 0; u < 4; ++u) {
        const float4 xv = xr[c + u];
        const float4 av = Ar[c + u];
        ss = fmaf(xv.x, av.x, ss);
        ss = fmaf(xv.y, av.y, ss);
        ss = fmaf(xv.z, av.z, ss);
        ss = fmaf(xv.w, av.w, ss);
      }
      s += ss;
    }
    part[seg][rank] = s;
    __syncthreads();
    if (threadIdx.x < 32) {
      float y = 0.f;
#pragma unroll
      for (int g = 0; g < 8; ++g) y += part[g][threadIdx.x];
      yv_s[threadIdx.x] = y;
    }
    __syncthreads();
    if (threadIdx.x == 0) {
      float ab[RANK];
#pragma unroll
      for (int r = 0; r < RANK; ++r) ab[r] = fabsf(yv_s[r] + dbias[r]);
      unsigned mask = 0;
#pragma unroll
      for (int k = 0; k < TOPK; ++k) {
        float best = -1.f;
        int bi = 0;
#pragma unroll
        for (int r = 0; r < RANK; ++r) {
          const bool sel = (((mask >> r) & 1u) == 0u) && (ab[r] > best);
          best = sel ? ab[r] : best;
          bi = sel ? r : bi;
        }
        mask |= 1u << bi;
      }
      mask_s = mask;
    }
    __syncthreads();
    if (threadIdx.x < 32) {
      const float v = ((mask_s >> rank) & 1u) ? 2.0f * yv_s[rank] : 0.f;
      w_pk[(size_t)t * RANK + rank] = (ushort)(__float_as_uint(v) >> 16);
    }
    __syncthreads();  // protect LDS reuse next iteration
  }
}

// ---------------- K3: out = w @ B^T via MFMA + LDS-coalesced store --------
// r19's MFMA k3 scattered 64B segments at 16KB stride (suspected write-
// efficiency regression). Fix: accumulate the block's 16tok x 256col slab
// in LDS (pad 260: MFMA-write 2-way banks = free; read canonical), then
// each wave stores 1KB-contiguous rows. Write-bound floor ~43us.
#define K3PAD 260

__global__ __launch_bounds__(256) void k3_mfma(const ushort* __restrict__ w_pk,
                                               const ushort* __restrict__ Bpk,
                                               float* __restrict__ out) {
  const int tid = threadIdx.x;
  const int lane = tid & 63;
  const int wid = __builtin_amdgcn_readfirstlane(tid >> 6);
  const int t0 = blockIdx.x * 16;
  const int c0 = blockIdx.y * 256;
  const int mrow = lane & 15;
  const int kg = lane >> 4;

  __shared__ float slab[16 * K3PAD];  // 16.6 KB

  const bf16x8 wf = *reinterpret_cast<const bf16x8*>(
      &w_pk[(size_t)(t0 + mrow) * RANK + kg * 8]);

#pragma unroll
  for (int jj = 0; jj < 4; ++jj) {
    const int ct = blockIdx.y * 16 + wid * 4 + jj;  // global 16-col tile
    const bf16x8 bf =
        *reinterpret_cast<const bf16x8*>(&Bpk[(size_t)ct * 512 + lane * 8]);
    f32x4 acc = {0.f, 0.f, 0.f, 0.f};
    acc = __builtin_amdgcn_mfma_f32_16x16x32_bf16(wf, bf, acc, 0, 0, 0);
    const int scol = (wid * 4 + jj) * 16 + mrow;  // 0..255 within slab
#pragma unroll
    for (int i = 0; i < 4; ++i) slab[(kg * 4 + i) * K3PAD + scol] = acc[i];
  }
  __syncthreads();

  // store: per jj each wave writes one full row = 1KB contiguous
#pragma unroll
  for (int jj = 0; jj < 4; ++jj) {
    const int idx = tid + jj * 256;  // 0..1023
    const int row = idx >> 6;        // 0..15 (uniform per wave)
    const int cq = idx & 63;         // float4 index within row
    const float4 v =
        *reinterpret_cast<const float4*>(&slab[row * K3PAD + cq * 4]);
    *reinterpret_cast<float4*>(
        &out[(size_t)(t0 + row) * DDIM + c0 + cq * 4]) = v;
  }
}

extern "C" void kernel_launch(void* const* d_in, const int* in_sizes, int n_in,
                              void* d_out, int out_size, void* d_ws,
                              size_t ws_size, hipStream_t stream) {
  const float* x = (const float*)d_in[0];
  const float* A = (const float*)d_in[1];
  const float* B = (const float*)d_in[2];
  const float* dbias = (const float*)d_in[3];
  float* out = (float*)d_out;

  const size_t plane = (size_t)TOKENS * RANK;     // 512K floats = 2 MB
  float* y_part = (float*)d_ws;                   // KCH planes (16 MB)
  ushort* w_pk = (ushort*)(y_part + KCH * plane); // 1 MB bf16
  bf16x8* Apk = (bf16x8*)(w_pk + (size_t)TOKENS * RANK);  // 512 KB
  ushort* Bpk = (ushort*)(Apk + 32768);           // 256 KB
  int* flag_cnt = (int*)(Bpk + (size_t)DDIM * RANK);
  int* flag_list = flag_cnt + 4;                  // capacity TOKENS (64 KB)

  k0_packA<<<128, 256, 0, stream>>>(A, Apk, flag_cnt);
  k0_packB<<<64, 256, 0, stream>>>(B, Bpk);
  k1_mfma<<<dim3(TOKENS / 64, KCH), 256, 0, stream>>>(x, Apk, y_part);
  k2_topk<<<TOKENS / 64, 64, 0, stream>>>(y_part, dbias, w_pk, flag_cnt,
                                          flag_list);
  k2b_refine<<<512, 256, 0, stream>>>(x, A, dbias, flag_cnt, flag_list, w_pk);
  k3_mfma<<<dim3(TOKENS / 16, DDIM / 256), 256, 0, stream>>>(w_pk, Bpk, out);
}

// Round 21
// 203.127 us; speedup vs baseline: 1.3993x; 1.0230x over previous
//
#include <hip/hip_runtime.h>

#define TOKENS 16384
#define DDIM 4096
#define RANK 32
#define TOPK 8
#define TAU 2e-3f    // routing-gap margin: flag if below
#define ROWF 260     // LDS floats per x row: 256 + 4 pad
#define NSUB 16      // 4096 dims / 256 per sub

typedef __attribute__((ext_vector_type(8))) short bf16x8;  // 8 bf16 (4 VGPR)
typedef __attribute__((ext_vector_type(4))) float f32x4;

// global -> LDS async DMA, 16B per lane (wave-uniform LDS base + lane*16)
__device__ __forceinline__ void dma16(const float* g, float* l) {
  __builtin_amdgcn_global_load_lds(
      (const __attribute__((address_space(1))) unsigned int*)g,
      (__attribute__((address_space(3))) unsigned int*)l, 16, 0, 0);
}

// ---------------- K0a: pack A into MFMA-fragment order, hi/lo bf16 --------
// Apk[(gks*4+s)*64 + lane], gks 0..127: 8 bf16 lane (mrow,kg) consumes at
// K-step gks, stream s (0:hi r<16, 1:hi r>=16, 2:lo r<16, 3:lo r>=16).
__global__ __launch_bounds__(256) void k0_packA(const float* __restrict__ A,
                                                bf16x8* __restrict__ Apk,
                                                int* __restrict__ flag_cnt) {
  const int i = blockIdx.x * 256 + threadIdx.x;  // 0 .. 32767
  if (i == 0) *flag_cnt = 0;
  const int lane = i & 63;
  const int s = (i >> 6) & 3;
  const int gks = i >> 8;  // 0..127
  const int mrow = lane & 15;
  const int kg = lane >> 4;
  const int row = (s & 1) ? mrow + 16 : mrow;
  const int col = gks * 32 + kg * 8;
  const float* src = &A[(size_t)row * DDIM + col];
  bf16x8 o;
#pragma unroll
  for (int j = 0; j < 8; ++j) {
    const float a = src[j];
    const unsigned b = __float_as_uint(a);
    if (s < 2) {
      o[j] = (short)(b >> 16);  // hi = truncate-to-bf16
    } else {
      const float hf = __uint_as_float(b & 0xFFFF0000u);
      const float r = a - hf;   // lo = residual as bf16
      o[j] = (short)(__float_as_uint(r) >> 16);
    }
  }
  Apk[i] = o;
}

// ---------------- K0b: pack B into MFMA B-operand fragment order ----------
__global__ __launch_bounds__(256) void k0_packB(const float* __restrict__ B,
                                                ushort* __restrict__ Bpk) {
  const int i = blockIdx.x * 256 + threadIdx.x;  // 0 .. 16383
  const int lane = i & 63;
  const int ct = i >> 6;
  const int col = ct * 16 + (lane & 15);
  const int r0 = (lane >> 4) * 8;
  const float* src = &B[(size_t)col * RANK + r0];
  bf16x8 o;
#pragma unroll
  for (int j = 0; j < 8; ++j)
    o[j] = (short)(__float_as_uint(src[j]) >> 16);
  *reinterpret_cast<bf16x8*>(&Bpk[(size_t)i * 8]) = o;
}

// ---------------- K1: y[t][r] via mfma_f32_16x16x32_bf16, KCH=1 -----------
// r18 counters: k1 was fill-wait-serialized (duration independent of HBM
// traffic, VALUBusy 9.5%). Fix: ONE block per 64-token tile does ALL 4096
// dims (grid=256, 1 block/CU) with 2-deep double-buffered DMA: prologue
// fills both buffers (32 DMAs in flight), steady loop waits vmcnt(16)
// (counted: only the oldest 16 = current sub; m135 semantics), computes 8
// K-steps, refills the consumed buffer for sub+2. Fill latency hides under
// a full sub of compute; waves stay barrier-free and decoupled.
__global__ __launch_bounds__(256) void k1_mfma(const float* __restrict__ x,
                                               const bf16x8* __restrict__ Apk,
                                               float* __restrict__ y) {
  const int tid = threadIdx.x;
  const int lane = tid & 63;
  const int wv = __builtin_amdgcn_readfirstlane(tid >> 6);
  const int t0 = blockIdx.x * 64 + wv * 16;

  __shared__ float xs[2 * 4 * 16 * ROWF];  // 133,120 B -> 1 block/CU
  float* b0 = &xs[(0 * 4 + wv) * 16 * ROWF];
  float* b1 = &xs[(1 * 4 + wv) * 16 * ROWF];

  const int mrow = lane & 15;  // token (A-op) / rank (B-op)
  const int kg = lane >> 4;    // k-group of 8 dims

  f32x4 acc0 = {0.f, 0.f, 0.f, 0.f};  // ranks 0..15
  f32x4 acc1 = {0.f, 0.f, 0.f, 0.f};  // ranks 16..31

  // prologue: fill sub0 -> b0, sub1 -> b1 (32 DMAs outstanding)
#pragma unroll
  for (int r = 0; r < 16; ++r)
    dma16(&x[(size_t)(t0 + r) * DDIM + lane * 4], b0 + r * ROWF);
#pragma unroll
  for (int r = 0; r < 16; ++r)
    dma16(&x[(size_t)(t0 + r) * DDIM + 256 + lane * 4], b1 + r * ROWF);

  for (int s = 0; s < NSUB; ++s) {
    // wait for THIS sub's 16 fills (oldest); keep next sub's 16 in flight
    if (s < NSUB - 1) {
      asm volatile("s_waitcnt vmcnt(16)" ::: "memory");
    } else {
      asm volatile("s_waitcnt vmcnt(0)" ::: "memory");
    }
    __builtin_amdgcn_sched_barrier(0);

    const float* buf = (s & 1) ? b1 : b0;
#pragma unroll
    for (int ks8 = 0; ks8 < 8; ++ks8) {
      const int gks = s * 8 + ks8;
      const float* xrow = buf + mrow * ROWF + ks8 * 32 + kg * 8;
      const float4 f0 = *reinterpret_cast<const float4*>(xrow);
      const float4 f1 = *reinterpret_cast<const float4*>(xrow + 4);

      const bf16x8 bh0 = Apk[(size_t)(gks * 4 + 0) * 64 + lane];
      const bf16x8 bh1 = Apk[(size_t)(gks * 4 + 1) * 64 + lane];
      const bf16x8 bl0 = Apk[(size_t)(gks * 4 + 2) * 64 + lane];
      const bf16x8 bl1 = Apk[(size_t)(gks * 4 + 3) * 64 + lane];

      const float xf[8] = {f0.x, f0.y, f0.z, f0.w, f1.x, f1.y, f1.z, f1.w};
      bf16x8 xh, xl;
#pragma unroll
      for (int j = 0; j < 8; ++j) {  // constant indices only (no scratch)
        const unsigned b = __float_as_uint(xf[j]);
        xh[j] = (short)(b >> 16);
        const float rr = xf[j] - __uint_as_float(b & 0xFFFF0000u);
        xl[j] = (short)(__float_as_uint(rr) >> 16);
      }

      acc0 = __builtin_amdgcn_mfma_f32_16x16x32_bf16(xh, bh0, acc0, 0, 0, 0);
      acc1 = __builtin_amdgcn_mfma_f32_16x16x32_bf16(xh, bh1, acc1, 0, 0, 0);
      acc0 = __builtin_amdgcn_mfma_f32_16x16x32_bf16(xh, bl0, acc0, 0, 0, 0);
      acc1 = __builtin_amdgcn_mfma_f32_16x16x32_bf16(xh, bl1, acc1, 0, 0, 0);
      acc0 = __builtin_amdgcn_mfma_f32_16x16x32_bf16(xl, bh0, acc0, 0, 0, 0);
      acc1 = __builtin_amdgcn_mfma_f32_16x16x32_bf16(xl, bh1, acc1, 0, 0, 0);
    }

    if (s + 2 < NSUB) {
      // this sub's ds_reads all returned (compiler lgkm waits precede the
      // MFMAs above) -> safe to overwrite the buffer with sub s+2
      asm volatile("s_waitcnt lgkmcnt(0)" ::: "memory");
      __builtin_amdgcn_sched_barrier(0);
      float* fb = (s & 1) ? b1 : b0;
#pragma unroll
      for (int r = 0; r < 16; ++r)
        dma16(&x[(size_t)(t0 + r) * DDIM + (s + 2) * 256 + lane * 4],
              fb + r * ROWF);
    }
  }

  // D: token = t0 + kg*4 + i, rank = mrow (acc0) / mrow+16 (acc1)
  float* yp = &y[(size_t)(t0 + kg * 4) * RANK + mrow];
#pragma unroll
  for (int i = 0; i < 4; ++i) {
    yp[(size_t)i * RANK] = acc0[i];
    yp[(size_t)i * RANK + 16] = acc1[i];
  }
}

// ---------------- K2: top-8 + gap margin; emit bf16 w_pk ------------------
__global__ __launch_bounds__(64) void k2_topk(const float* __restrict__ y,
                                              const float* __restrict__ dbias,
                                              ushort* __restrict__ w_pk,
                                              int* __restrict__ flag_cnt,
                                              int* __restrict__ flag_list) {
  const int t = blockIdx.x * 64 + threadIdx.x;
  float yv[RANK];
  const float* yp = &y[(size_t)t * RANK];
#pragma unroll
  for (int q = 0; q < RANK / 4; ++q) {
    const float4 v = reinterpret_cast<const float4*>(yp)[q];
    yv[q * 4 + 0] = v.x; yv[q * 4 + 1] = v.y;
    yv[q * 4 + 2] = v.z; yv[q * 4 + 3] = v.w;
  }

  float ab[RANK];
#pragma unroll
  for (int r = 0; r < RANK; ++r) ab[r] = fabsf(yv[r] + dbias[r]);

  unsigned mask = 0;
  float best8 = 0.f;
#pragma unroll
  for (int k = 0; k < TOPK; ++k) {
    float best = -1.f;
    int bi = 0;
#pragma unroll
    for (int r = 0; r < RANK; ++r) {
      // strict > keeps lowest index on ties == jax.lax.top_k stability
      const bool sel = (((mask >> r) & 1u) == 0u) && (ab[r] > best);
      best = sel ? ab[r] : best;
      bi = sel ? r : bi;
    }
    mask |= 1u << bi;
    best8 = best;
  }
  float ninth = -1.f;
#pragma unroll
  for (int r = 0; r < RANK; ++r) {
    const bool un = ((mask >> r) & 1u) == 0u;
    ninth = (un && ab[r] > ninth) ? ab[r] : ninth;
  }
  if (best8 - ninth < TAU) {  // split-y can't certify fp32 decision
    const int idx = atomicAdd(flag_cnt, 1);
    flag_list[idx] = t;
  }

  // w = 2*y*mask, packed to bf16 (natural rank order == A-op fragment order)
  ushort* wp = &w_pk[(size_t)t * RANK];
  unsigned up[16];
#pragma unroll
  for (int h = 0; h < 16; ++h) {
    const float a = ((mask >> (2 * h)) & 1u) ? 2.0f * yv[2 * h] : 0.f;
    const float b = ((mask >> (2 * h + 1)) & 1u) ? 2.0f * yv[2 * h + 1] : 0.f;
    up[h] = (__float_as_uint(a) >> 16) | (__float_as_uint(b) & 0xFFFF0000u);
  }
#pragma unroll
  for (int q = 0; q < 4; ++q) {
    uint4 v = {up[4 * q], up[4 * q + 1], up[4 * q + 2], up[4 * q + 3]};
    reinterpret_cast<uint4*>(wp)[q] = v;
  }
}

// ---------------- K2b: exact fp32 re-route for flagged tokens -------------
__global__ __launch_bounds__(256) void k2b_refine(
    const float* __restrict__ x, const float* __restrict__ A,
    const float* __restrict__ dbias, const int* __restrict__ flag_cnt,
    const int* __restrict__ flag_list, ushort* __restrict__ w_pk) {
  __shared__ float part[8][RANK];
  __shared__ float yv_s[RANK];
  __shared__ unsigned mask_s;
  const int cnt = *flag_cnt;
  const int rank = threadIdx.x & 31;
  const int seg = threadIdx.x >> 5;

  for (int i = blockIdx.x; i < cnt; i += gridDim.x) {
    const int t = flag_list[i];
    const float4* xr =
        reinterpret_cast<const float4*>(&x[(size_t)t * DDIM + seg * 512]);
    const float4* Ar =
        reinterpret_cast<const float4*>(&A[(size_t)rank * DDIM + seg * 512]);
    float s = 0.f;
    for (int c = 0; c < 128; c += 4) {  // 16-dim sub-sums, two-level fp32
      float ss = 0.f;
#pragma unroll
      for (int u = 0; u < 4; ++u) {
        const float4 xv = xr[c + u];
        const float4 av = Ar[c + u];
        ss = fmaf(xv.x, av.x, ss);
        ss = fmaf(xv.y, av.y, ss);
        ss = fmaf(xv.z, av.z, ss);
        ss = fmaf(xv.w, av.w, ss);
      }
      s += ss;
    }
    part[seg][rank] = s;
    __syncthreads();
    if (threadIdx.x < 32) {
      float yy = 0.f;
#pragma unroll
      for (int g = 0; g < 8; ++g) yy += part[g][threadIdx.x];
      yv_s[threadIdx.x] = yy;
    }
    __syncthreads();
    if (threadIdx.x == 0) {
      float ab[RANK];
#pragma unroll
      for (int r = 0; r < RANK; ++r) ab[r] = fabsf(yv_s[r] + dbias[r]);
      unsigned mask = 0;
#pragma unroll
      for (int k = 0; k < TOPK; ++k) {
        float best = -1.f;
        int bi = 0;
#pragma unroll
        for (int r = 0; r < RANK; ++r) {
          const bool sel = (((mask >> r) & 1u) == 0u) && (ab[r] > best);
          best = sel ? ab[r] : best;
          bi = sel ? r : bi;
        }
        mask |= 1u << bi;
      }
      mask_s = mask;
    }
    __syncthreads();
    if (threadIdx.x < 32) {
      const float v = ((mask_s >> rank) & 1u) ? 2.0f * yv_s[rank] : 0.f;
      w_pk[(size_t)t * RANK + rank] = (ushort)(__float_as_uint(v) >> 16);
    }
    __syncthreads();  // protect LDS reuse next iteration
  }
}

// ---------------- K3: out = w @ B^T via MFMA + LDS-coalesced store --------
// r20-proven: MFMA kills the DS-broadcast serialization; LDS slab makes
// stores 1KB-contiguous. Write-bound, ~50us.
#define K3PAD 260

__global__ __launch_bounds__(256) void k3_mfma(const ushort* __restrict__ w_pk,
                                               const ushort* __restrict__ Bpk,
                                               float* __restrict__ out) {
  const int tid = threadIdx.x;
  const int lane = tid & 63;
  const int wid = __builtin_amdgcn_readfirstlane(tid >> 6);
  const int t0 = blockIdx.x * 16;
  const int c0 = blockIdx.y * 256;
  const int mrow = lane & 15;
  const int kg = lane >> 4;

  __shared__ float slab[16 * K3PAD];  // 16.6 KB

  const bf16x8 wf = *reinterpret_cast<const bf16x8*>(
      &w_pk[(size_t)(t0 + mrow) * RANK + kg * 8]);

#pragma unroll
  for (int jj = 0; jj < 4; ++jj) {
    const int ct = blockIdx.y * 16 + wid * 4 + jj;  // global 16-col tile
    const bf16x8 bf =
        *reinterpret_cast<const bf16x8*>(&Bpk[(size_t)ct * 512 + lane * 8]);
    f32x4 acc = {0.f, 0.f, 0.f, 0.f};
    acc = __builtin_amdgcn_mfma_f32_16x16x32_bf16(wf, bf, acc, 0, 0, 0);
    const int scol = (wid * 4 + jj) * 16 + mrow;  // 0..255 within slab
#pragma unroll
    for (int i = 0; i < 4; ++i) slab[(kg * 4 + i) * K3PAD + scol] = acc[i];
  }
  __syncthreads();

  // store: each wave writes full rows, 1KB contiguous
#pragma unroll
  for (int jj = 0; jj < 4; ++jj) {
    const int idx = tid + jj * 256;  // 0..1023
    const int row = idx >> 6;        // 0..15 (uniform per wave)
    const int cq = idx & 63;         // float4 index within row
    const float4 v =
        *reinterpret_cast<const float4*>(&slab[row * K3PAD + cq * 4]);
    *reinterpret_cast<float4*>(
        &out[(size_t)(t0 + row) * DDIM + c0 + cq * 4]) = v;
  }
}

extern "C" void kernel_launch(void* const* d_in, const int* in_sizes, int n_in,
                              void* d_out, int out_size, void* d_ws,
                              size_t ws_size, hipStream_t stream) {
  const float* x = (const float*)d_in[0];
  const float* A = (const float*)d_in[1];
  const float* B = (const float*)d_in[2];
  const float* dbias = (const float*)d_in[3];
  float* out = (float*)d_out;

  const size_t plane = (size_t)TOKENS * RANK;     // 512K floats = 2 MB
  float* y = (float*)d_ws;                        // 1 plane (2 MB)
  ushort* w_pk = (ushort*)(y + plane);            // 1 MB bf16
  bf16x8* Apk = (bf16x8*)(w_pk + (size_t)TOKENS * RANK);  // 512 KB
  ushort* Bpk = (ushort*)(Apk + 32768);           // 256 KB
  int* flag_cnt = (int*)(Bpk + (size_t)DDIM * RANK);
  int* flag_list = flag_cnt + 4;                  // capacity TOKENS (64 KB)

  k0_packA<<<128, 256, 0, stream>>>(A, Apk, flag_cnt);
  k0_packB<<<64, 256, 0, stream>>>(B, Bpk);
  k1_mfma<<<TOKENS / 64, 256, 0, stream>>>(x, Apk, y);
  k2_topk<<<TOKENS / 64, 64, 0, stream>>>(y, dbias, w_pk, flag_cnt,
                                          flag_list);
  k2b_refine<<<512, 256, 0, stream>>>(x, A, dbias, flag_cnt, flag_list, w_pk);
  k3_mfma<<<dim3(TOKENS / 16, DDIM / 256), 256, 0, stream>>>(w_pk, Bpk, out);
}

// Round 22
// 200.647 us; speedup vs baseline: 1.4166x; 1.0124x over previous
//
#include <hip/hip_runtime.h>

#define TOKENS 16384
#define DDIM 4096
#define RANK 32
#define TOPK 8
#define TAU 2e-3f    // routing-gap margin: flag if below
#define PRF 260      // LDS floats per row-PAIR: 2x128 + 4 pad
#define NSUB 16      // per-wave: 2048 dims / 128 per sub

typedef __attribute__((ext_vector_type(8))) short bf16x8;  // 8 bf16 (4 VGPR)
typedef __attribute__((ext_vector_type(4))) float f32x4;

// global -> LDS async DMA, 16B per lane; dest = wave-uniform base + lane*16
__device__ __forceinline__ void dma16(const float* g, float* l) {
  __builtin_amdgcn_global_load_lds(
      (const __attribute__((address_space(1))) unsigned int*)g,
      (__attribute__((address_space(3))) unsigned int*)l, 16, 0, 0);
}

// ---------------- K0a: pack A into MFMA-fragment order, hi/lo bf16 --------
// Apk[(gks*4+s)*64+lane], gks 0..127; s: 0=hi r<16, 1=hi r>=16, 2=lo, 3=lo hi-half.
__global__ __launch_bounds__(256) void k0_packA(const float* __restrict__ A,
                                                bf16x8* __restrict__ Apk,
                                                int* __restrict__ flag_cnt) {
  const int i = blockIdx.x * 256 + threadIdx.x;  // 0 .. 32767
  if (i == 0) *flag_cnt = 0;
  const int lane = i & 63;
  const int s = (i >> 6) & 3;
  const int gks = i >> 8;  // 0..127
  const int mrow = lane & 15;
  const int kg = lane >> 4;
  const int row = (s & 1) ? mrow + 16 : mrow;
  const int col = gks * 32 + kg * 8;
  const float* src = &A[(size_t)row * DDIM + col];
  bf16x8 o;
#pragma unroll
  for (int j = 0; j < 8; ++j) {
    const float a = src[j];
    const unsigned b = __float_as_uint(a);
    if (s < 2) {
      o[j] = (short)(b >> 16);  // hi = truncate-to-bf16
    } else {
      const float hf = __uint_as_float(b & 0xFFFF0000u);
      const float r = a - hf;   // lo = residual as bf16
      o[j] = (short)(__float_as_uint(r) >> 16);
    }
  }
  Apk[i] = o;
}

// ---------------- K0b: pack B into MFMA B-operand fragment order ----------
__global__ __launch_bounds__(256) void k0_packB(const float* __restrict__ B,
                                                ushort* __restrict__ Bpk) {
  const int i = blockIdx.x * 256 + threadIdx.x;  // 0 .. 16383
  const int lane = i & 63;
  const int ct = i >> 6;
  const int col = ct * 16 + (lane & 15);
  const int r0 = (lane >> 4) * 8;
  const float* src = &B[(size_t)col * RANK + r0];
  bf16x8 o;
#pragma unroll
  for (int j = 0; j < 8; ++j)
    o[j] = (short)(__float_as_uint(src[j]) >> 16);
  *reinterpret_cast<bf16x8*>(&Bpk[(size_t)i * 8]) = o;
}

// ---------------- K1: y + top-8 + w_pk, fused; K-split 2-wave blocks ------
// 1024 blocks x 128 thr: 16 tokens/block, wave w owns dims w*2048..+2047.
// 37.5 KB LDS -> 4 blocks/CU = 8 waves/CU (2x every prior variant) AND each
// wave runs the 2-deep counted-vmcnt pipeline -> fills always in flight.
// Sub = 128 dims staged as 8 row-PAIR DMAs (1KB each: lanes 0-31 row 2p,
// lanes 32-63 row 2p+1 via per-lane SOURCE; dest linear). Pair stride 260
// floats -> ds_read_b128 2-way banked = free. Epilogue: both waves' partial
// acc -> LDS, 16 threads sum + top-8 + TAU flag + bf16 w_pk (fuses old k2).
__global__ __launch_bounds__(128) void k1_fused(const float* __restrict__ x,
                                                const bf16x8* __restrict__ Apk,
                                                const float* __restrict__ dbias,
                                                ushort* __restrict__ w_pk,
                                                int* __restrict__ flag_cnt,
                                                int* __restrict__ flag_list) {
  const int tid = threadIdx.x;
  const int lane = tid & 63;
  const int wv = __builtin_amdgcn_readfirstlane(tid >> 6);  // K-half
  const int t0 = blockIdx.x * 16;
  const int db0 = wv * 2048;  // this wave's dim base

  __shared__ float xs[2 * 2 * 8 * PRF];  // [wave][buf][pair][260] = 33.28 KB
  __shared__ float yl[2 * 16 * 33];      // partial y, +1-pad rows = 4.2 KB
  float* b0 = &xs[(wv * 2 + 0) * 8 * PRF];
  float* b1 = &xs[(wv * 2 + 1) * 8 * PRF];

  const int mrow = lane & 15;  // token (A-op) / rank (B-op)
  const int kg = lane >> 4;    // k-group of 8 dims

  // per-lane DMA source offsets: lanes 0-31 -> row 2p, 32-63 -> row 2p+1
  const int srow = lane >> 5;          // 0/1 within pair
  const int scol = (lane & 31) * 4;    // float offset 0..124

  f32x4 acc0 = {0.f, 0.f, 0.f, 0.f};  // ranks 0..15
  f32x4 acc1 = {0.f, 0.f, 0.f, 0.f};  // ranks 16..31

  // prologue: fill sub0 -> b0, sub1 -> b1 (16 DMAs outstanding)
#pragma unroll
  for (int p = 0; p < 8; ++p)
    dma16(&x[(size_t)(t0 + 2 * p + srow) * DDIM + db0 + scol], b0 + p * PRF);
#pragma unroll
  for (int p = 0; p < 8; ++p)
    dma16(&x[(size_t)(t0 + 2 * p + srow) * DDIM + db0 + 128 + scol],
          b1 + p * PRF);

  for (int s = 0; s < NSUB; ++s) {
    if (s < NSUB - 1) {
      asm volatile("s_waitcnt vmcnt(8)" ::: "memory");  // sub s landed
    } else {
      asm volatile("s_waitcnt vmcnt(0)" ::: "memory");
    }
    __builtin_amdgcn_sched_barrier(0);

    const float* buf = (s & 1) ? b1 : b0;
    const int gksb = wv * 64 + s * 4;
#pragma unroll
    for (int k4 = 0; k4 < 4; ++k4) {
      const int gks = gksb + k4;
      // row mrow: pair mrow>>1, half mrow&1
      const float* xrow =
          buf + (mrow >> 1) * PRF + (mrow & 1) * 128 + k4 * 32 + kg * 8;
      const float4 f0 = *reinterpret_cast<const float4*>(xrow);
      const float4 f1 = *reinterpret_cast<const float4*>(xrow + 4);

      const bf16x8 bh0 = Apk[(size_t)(gks * 4 + 0) * 64 + lane];
      const bf16x8 bh1 = Apk[(size_t)(gks * 4 + 1) * 64 + lane];
      const bf16x8 bl0 = Apk[(size_t)(gks * 4 + 2) * 64 + lane];
      const bf16x8 bl1 = Apk[(size_t)(gks * 4 + 3) * 64 + lane];

      const float xf[8] = {f0.x, f0.y, f0.z, f0.w, f1.x, f1.y, f1.z, f1.w};
      bf16x8 xh, xl;
#pragma unroll
      for (int j = 0; j < 8; ++j) {  // constant indices only (no scratch)
        const unsigned b = __float_as_uint(xf[j]);
        xh[j] = (short)(b >> 16);
        const float rr = xf[j] - __uint_as_float(b & 0xFFFF0000u);
        xl[j] = (short)(__float_as_uint(rr) >> 16);
      }

      acc0 = __builtin_amdgcn_mfma_f32_16x16x32_bf16(xh, bh0, acc0, 0, 0, 0);
      acc1 = __builtin_amdgcn_mfma_f32_16x16x32_bf16(xh, bh1, acc1, 0, 0, 0);
      acc0 = __builtin_amdgcn_mfma_f32_16x16x32_bf16(xh, bl0, acc0, 0, 0, 0);
      acc1 = __builtin_amdgcn_mfma_f32_16x16x32_bf16(xh, bl1, acc1, 0, 0, 0);
      acc0 = __builtin_amdgcn_mfma_f32_16x16x32_bf16(xl, bh0, acc0, 0, 0, 0);
      acc1 = __builtin_amdgcn_mfma_f32_16x16x32_bf16(xl, bh1, acc1, 0, 0, 0);
    }

    if (s + 2 < NSUB) {
      // this sub's ds_reads are complete before buffer overwrite
      asm volatile("s_waitcnt lgkmcnt(0)" ::: "memory");
      __builtin_amdgcn_sched_barrier(0);
      float* fb = (s & 1) ? b1 : b0;
      const int db = db0 + (s + 2) * 128;
#pragma unroll
      for (int p = 0; p < 8; ++p)
        dma16(&x[(size_t)(t0 + 2 * p + srow) * DDIM + db + scol],
              fb + p * PRF);
    }
  }

  // ---- fused epilogue: combine K-halves, top-8, flag, bf16 w_pk ----
  // lane (mrow,kg): token = kg*4+i, rank = mrow / mrow+16
#pragma unroll
  for (int i = 0; i < 4; ++i) {
    yl[(wv * 16 + kg * 4 + i) * 33 + mrow] = acc0[i];
    yl[(wv * 16 + kg * 4 + i) * 33 + mrow + 16] = acc1[i];
  }
  __syncthreads();

  if (tid < 16) {
    const int t = t0 + tid;
    float yv[RANK];
#pragma unroll
    for (int r = 0; r < RANK; ++r)
      yv[r] = yl[tid * 33 + r] + yl[(16 + tid) * 33 + r];

    float ab[RANK];
#pragma unroll
    for (int r = 0; r < RANK; ++r) ab[r] = fabsf(yv[r] + dbias[r]);

    unsigned mask = 0;
    float best8 = 0.f;
#pragma unroll
    for (int k = 0; k < TOPK; ++k) {
      float best = -1.f;
      int bi = 0;
#pragma unroll
      for (int r = 0; r < RANK; ++r) {
        // strict > keeps lowest index on ties == jax.lax.top_k stability
        const bool sel = (((mask >> r) & 1u) == 0u) && (ab[r] > best);
        best = sel ? ab[r] : best;
        bi = sel ? r : bi;
      }
      mask |= 1u << bi;
      best8 = best;
    }
    float ninth = -1.f;
#pragma unroll
    for (int r = 0; r < RANK; ++r) {
      const bool un = ((mask >> r) & 1u) == 0u;
      ninth = (un && ab[r] > ninth) ? ab[r] : ninth;
    }
    if (best8 - ninth < TAU) {  // split-y can't certify fp32 decision
      const int idx = atomicAdd(flag_cnt, 1);
      flag_list[idx] = t;
    }

    ushort* wp = &w_pk[(size_t)t * RANK];
    unsigned up[16];
#pragma unroll
    for (int h = 0; h < 16; ++h) {
      const float a = ((mask >> (2 * h)) & 1u) ? 2.0f * yv[2 * h] : 0.f;
      const float b =
          ((mask >> (2 * h + 1)) & 1u) ? 2.0f * yv[2 * h + 1] : 0.f;
      up[h] = (__float_as_uint(a) >> 16) | (__float_as_uint(b) & 0xFFFF0000u);
    }
#pragma unroll
    for (int q = 0; q < 4; ++q) {
      uint4 v = {up[4 * q], up[4 * q + 1], up[4 * q + 2], up[4 * q + 3]};
      reinterpret_cast<uint4*>(wp)[q] = v;
    }
  }
}

// ---------------- K2b: exact fp32 re-route for flagged tokens -------------
__global__ __launch_bounds__(256) void k2b_refine(
    const float* __restrict__ x, const float* __restrict__ A,
    const float* __restrict__ dbias, const int* __restrict__ flag_cnt,
    const int* __restrict__ flag_list, ushort* __restrict__ w_pk) {
  __shared__ float part[8][RANK];
  __shared__ float yv_s[RANK];
  __shared__ unsigned mask_s;
  const int cnt = *flag_cnt;
  const int rank = threadIdx.x & 31;
  const int seg = threadIdx.x >> 5;

  for (int i = blockIdx.x; i < cnt; i += gridDim.x) {
    const int t = flag_list[i];
    const float4* xr =
        reinterpret_cast<const float4*>(&x[(size_t)t * DDIM + seg * 512]);
    const float4* Ar =
        reinterpret_cast<const float4*>(&A[(size_t)rank * DDIM + seg * 512]);
    float s = 0.f;
    for (int c = 0; c < 128; c += 4) {  // 16-dim sub-sums, two-level fp32
      float ss = 0.f;
#pragma unroll
      for (int u = 0; u < 4; ++u) {
        const float4 xv = xr[c + u];
        const float4 av = Ar[c + u];
        ss = fmaf(xv.x, av.x, ss);
        ss = fmaf(xv.y, av.y, ss);
        ss = fmaf(xv.z, av.z, ss);
        ss = fmaf(xv.w, av.w, ss);
      }
      s += ss;
    }
    part[seg][rank] = s;
    __syncthreads();
    if (threadIdx.x < 32) {
      float yy = 0.f;
#pragma unroll
      for (int g = 0; g < 8; ++g) yy += part[g][threadIdx.x];
      yv_s[threadIdx.x] = yy;
    }
    __syncthreads();
    if (threadIdx.x == 0) {
      float ab[RANK];
#pragma unroll
      for (int r = 0; r < RANK; ++r) ab[r] = fabsf(yv_s[r] + dbias[r]);
      unsigned mask = 0;
#pragma unroll
      for (int k = 0; k < TOPK; ++k) {
        float best = -1.f;
        int bi = 0;
#pragma unroll
        for (int r = 0; r < RANK; ++r) {
          const bool sel = (((mask >> r) & 1u) == 0u) && (ab[r] > best);
          best = sel ? ab[r] : best;
          bi = sel ? r : bi;
        }
        mask |= 1u << bi;
      }
      mask_s = mask;
    }
    __syncthreads();
    if (threadIdx.x < 32) {
      const float v = ((mask_s >> rank) & 1u) ? 2.0f * yv_s[rank] : 0.f;
      w_pk[(size_t)t * RANK + rank] = (ushort)(__float_as_uint(v) >> 16);
    }
    __syncthreads();  // protect LDS reuse next iteration
  }
}

// ---------------- K3: out = w @ B^T via MFMA + LDS-coalesced store --------
#define K3PAD 260

__global__ __launch_bounds__(256) void k3_mfma(const ushort* __restrict__ w_pk,
                                               const ushort* __restrict__ Bpk,
                                               float* __restrict__ out) {
  const int tid = threadIdx.x;
  const int lane = tid & 63;
  const int wid = __builtin_amdgcn_readfirstlane(tid >> 6);
  const int t0 = blockIdx.x * 16;
  const int c0 = blockIdx.y * 256;
  const int mrow = lane & 15;
  const int kg = lane >> 4;

  __shared__ float slab[16 * K3PAD];  // 16.6 KB

  const bf16x8 wf = *reinterpret_cast<const bf16x8*>(
      &w_pk[(size_t)(t0 + mrow) * RANK + kg * 8]);

#pragma unroll
  for (int jj = 0; jj < 4; ++jj) {
    const int ct = blockIdx.y * 16 + wid * 4 + jj;  // global 16-col tile
    const bf16x8 bf =
        *reinterpret_cast<const bf16x8*>(&Bpk[(size_t)ct * 512 + lane * 8]);
    f32x4 acc = {0.f, 0.f, 0.f, 0.f};
    acc = __builtin_amdgcn_mfma_f32_16x16x32_bf16(wf, bf, acc, 0, 0, 0);
    const int scol = (wid * 4 + jj) * 16 + mrow;  // 0..255 within slab
#pragma unroll
    for (int i = 0; i < 4; ++i) slab[(kg * 4 + i) * K3PAD + scol] = acc[i];
  }
  __syncthreads();

  // store: each wave writes full rows, 1KB contiguous
#pragma unroll
  for (int jj = 0; jj < 4; ++jj) {
    const int idx = tid + jj * 256;  // 0..1023
    const int row = idx >> 6;        // 0..15 (uniform per wave)
    const int cq = idx & 63;         // float4 index within row
    const float4 v =
        *reinterpret_cast<const float4*>(&slab[row * K3PAD + cq * 4]);
    *reinterpret_cast<float4*>(
        &out[(size_t)(t0 + row) * DDIM + c0 + cq * 4]) = v;
  }
}

extern "C" void kernel_launch(void* const* d_in, const int* in_sizes, int n_in,
                              void* d_out, int out_size, void* d_ws,
                              size_t ws_size, hipStream_t stream) {
  const float* x = (const float*)d_in[0];
  const float* A = (const float*)d_in[1];
  const float* B = (const float*)d_in[2];
  const float* dbias = (const float*)d_in[3];
  float* out = (float*)d_out;

  ushort* w_pk = (ushort*)d_ws;                   // 1 MB bf16
  bf16x8* Apk = (bf16x8*)(w_pk + (size_t)TOKENS * RANK);  // 512 KB
  ushort* Bpk = (ushort*)(Apk + 32768);           // 256 KB
  int* flag_cnt = (int*)(Bpk + (size_t)DDIM * RANK);
  int* flag_list = flag_cnt + 4;                  // capacity TOKENS (64 KB)

  k0_packA<<<128, 256, 0, stream>>>(A, Apk, flag_cnt);
  k0_packB<<<64, 256, 0, stream>>>(B, Bpk);
  k1_fused<<<TOKENS / 16, 128, 0, stream>>>(x, Apk, dbias, w_pk, flag_cnt,
                                            flag_list);
  k2b_refine<<<512, 256, 0, stream>>>(x, A, dbias, flag_cnt, flag_list, w_pk);
  k3_mfma<<<dim3(TOKENS / 16, DDIM / 256), 256, 0, stream>>>(w_pk, Bpk, out);
}